// Round 1
// baseline (419.061 us; speedup 1.0000x reference)
//
#include <hip/hip_runtime.h>
#include <cstddef>
#include <cstdint>

// Problem constants
#define B_    8
#define C_    256
#define Himg  80
#define Wimg  80
#define HW_   6400
#define NH_   8
#define NP_   4
#define CPH_  32
#define MPROJ 352   // 256 value + 64 offsets + 32 attn
#define MPAD  384   // padded to multiple of 64 for tiling

// ---------------------------------------------------------------------------
// Kernel 0: build concatenated weight matrix Wcat[384][256] and bias bcat[384]
// rows 0..255 = Wv, 256..319 = Woff, 320..351 = Wa, 352..383 = 0
// ---------------------------------------------------------------------------
__global__ __launch_bounds__(256) void prep_wcat(
        const float* __restrict__ Wv,  const float* __restrict__ bv,
        const float* __restrict__ Woff, const float* __restrict__ boff,
        const float* __restrict__ Wa,  const float* __restrict__ ba,
        float* __restrict__ Wcat, float* __restrict__ bcat) {
    int o = blockIdx.x;          // 0..383
    int t = threadIdx.x;         // 0..255
    const float* src = nullptr;
    float bias = 0.f;
    if (o < 256)       { src = Wv   + (size_t)o * 256;        bias = bv[o];        }
    else if (o < 320)  { src = Woff + (size_t)(o - 256) * 256; bias = boff[o - 256]; }
    else if (o < 352)  { src = Wa   + (size_t)(o - 320) * 256; bias = ba[o - 320];  }
    Wcat[(size_t)o * 256 + t] = src ? src[t] : 0.f;
    if (t == 0) bcat[o] = bias;
}

// ---------------------------------------------------------------------------
// Kernel 1: projection GEMM.
// proj[(b*HW + p)*352 + o] = sum_k Wcat[o][k] * x[b][k][p] + bcat[o]
// Tiling: BM=64 (o), BN=64 (p), BK=32. 256 threads, 4x4 micro-tile.
// Thread o-contiguous (tx*4+j) so stores are float4 in the pixel-major row.
// ---------------------------------------------------------------------------
__global__ __launch_bounds__(256) void gemm_proj(
        const float* __restrict__ x, const float* __restrict__ Wcat,
        const float* __restrict__ bcat, float* __restrict__ proj) {
    __shared__ float As[32][68];   // [k][o]
    __shared__ float Bs[32][68];   // [k][p]
    const int b  = blockIdx.z;
    const int o0 = blockIdx.y * 64;
    const int p0 = blockIdx.x * 64;
    const int t  = threadIdx.x;
    const int tx = t & 15;   // o-group: o = o0 + tx*4 + j
    const int ty = t >> 4;   // p-group: p = p0 + ty*4 + i
    const float* xb = x + (size_t)b * C_ * HW_;
    float acc[4][4] = {};    // [i:p][j:o]

    for (int k0 = 0; k0 < 256; k0 += 32) {
        // A tile: Wcat rows o0..o0+63, cols k0..k0+31 -> As[k][o] (transposed)
        #pragma unroll
        for (int r = 0; r < 2; ++r) {
            int flat = t + r * 256;          // 0..511
            int o    = flat >> 3;            // 0..63
            int k4   = (flat & 7) << 2;      // 0,4,...,28
            float4 w4 = *(const float4*)(Wcat + (size_t)(o0 + o) * 256 + k0 + k4);
            As[k4 + 0][o] = w4.x; As[k4 + 1][o] = w4.y;
            As[k4 + 2][o] = w4.z; As[k4 + 3][o] = w4.w;
        }
        // B tile: x[b][k0+k][p0..p0+63] -> Bs[k][p]; float4 along p (coalesced)
        #pragma unroll
        for (int r = 0; r < 2; ++r) {
            int flat = t + r * 256;
            int k    = flat >> 4;            // 0..31
            int p4   = (flat & 15) << 2;     // 0..60
            *(float4*)(&Bs[k][p4]) =
                *(const float4*)(xb + (size_t)(k0 + k) * HW_ + p0 + p4);
        }
        __syncthreads();
        #pragma unroll
        for (int kk = 0; kk < 32; ++kk) {
            float4 av = *(const float4*)(&As[kk][tx * 4]);
            float4 bv4 = *(const float4*)(&Bs[kk][ty * 4]);
            float aa[4] = {av.x, av.y, av.z, av.w};
            float bb[4] = {bv4.x, bv4.y, bv4.z, bv4.w};
            #pragma unroll
            for (int i = 0; i < 4; ++i)
                #pragma unroll
                for (int j = 0; j < 4; ++j)
                    acc[i][j] += bb[i] * aa[j];
        }
        __syncthreads();
    }

    const int ocol = o0 + tx * 4;
    if (ocol + 3 < MPROJ) {               // rows 352..383 are padding
        float b0 = bcat[ocol + 0], b1 = bcat[ocol + 1];
        float b2 = bcat[ocol + 2], b3 = bcat[ocol + 3];
        #pragma unroll
        for (int i = 0; i < 4; ++i) {
            int p = p0 + ty * 4 + i;
            float4 r;
            r.x = acc[i][0] + b0; r.y = acc[i][1] + b1;
            r.z = acc[i][2] + b2; r.w = acc[i][3] + b3;
            *(float4*)(proj + ((size_t)b * HW_ + p) * MPROJ + ocol) = r;
        }
    }
}

// ---------------------------------------------------------------------------
// Kernel 2: softmax + bilinear sampling + point-weighted sum.
// Block = 256 threads = 8 pixels x 32 channels; grid (HW/8, NH, B).
// proj row layout per pixel: [0..255]=value, [256..319]=offsets, [320..351]=attn
// weighted[(b*HW+p)*256 + h*32 + cc]
// ---------------------------------------------------------------------------
__global__ __launch_bounds__(256) void sample_kern(
        const float* __restrict__ proj, float* __restrict__ weighted) {
    const int t  = threadIdx.x;
    const int cc = t & 31;
    const int ps = t >> 5;
    const int h  = blockIdx.y;
    const int b  = blockIdx.z;
    const int p  = blockIdx.x * 8 + ps;
    const int yy = p / Wimg;
    const int xx = p - yy * Wimg;

    const float* row = proj + ((size_t)b * HW_ + p) * MPROJ;

    // softmax over the 4 points of this head
    float l0 = row[320 + h * 4 + 0];
    float l1 = row[320 + h * 4 + 1];
    float l2 = row[320 + h * 4 + 2];
    float l3 = row[320 + h * 4 + 3];
    float m  = fmaxf(fmaxf(l0, l1), fmaxf(l2, l3));
    float e0 = expf(l0 - m), e1 = expf(l1 - m), e2 = expf(l2 - m), e3 = expf(l3 - m);
    float inv = 1.f / (e0 + e1 + e2 + e3);
    float wgt[4] = {e0 * inv, e1 * inv, e2 * inv, e3 * inv};

    const float* vbase = proj + (size_t)b * HW_ * MPROJ + h * CPH_ + cc;

    float acc = 0.f;
    #pragma unroll
    for (int pt = 0; pt < NP_; ++pt) {
        float offx = row[256 + (h * NP_ + pt) * 2 + 0];
        float offy = row[256 + (h * NP_ + pt) * 2 + 1];
        // ix = (gx + offx + 1)*0.5*(W-1) with gx = -1 + 2*xx/(W-1)  ->  xx + offx*39.5
        float ix = (float)xx + offx * 0.5f * (Wimg - 1);
        float iy = (float)yy + offy * 0.5f * (Himg - 1);
        float x0f = floorf(ix), y0f = floorf(iy);
        int   x0  = (int)x0f,   y0  = (int)y0f;
        float wx1 = ix - x0f, wx0 = 1.f - wx1;
        float wy1 = iy - y0f, wy0 = 1.f - wy1;
        float s = 0.f;
        #pragma unroll
        for (int dy = 0; dy < 2; ++dy) {
            int yc = y0 + dy;
            if (yc < 0 || yc > Himg - 1) continue;
            float wy = dy ? wy1 : wy0;
            #pragma unroll
            for (int dx = 0; dx < 2; ++dx) {
                int xc = x0 + dx;
                if (xc < 0 || xc > Wimg - 1) continue;
                float wx = dx ? wx1 : wx0;
                s += wy * wx * vbase[(size_t)(yc * Wimg + xc) * MPROJ];
            }
        }
        acc += wgt[pt] * s;
    }
    weighted[((size_t)b * HW_ + p) * C_ + h * CPH_ + cc] = acc;
}

// ---------------------------------------------------------------------------
// Kernel 3: output GEMM + bias + residual.
// out[b][o][p] = sum_k Wo[o][k] * weighted[(b*HW+p)*256 + k] + bo[o] + x[b][o][p]
// Thread p-contiguous (tx*4+j) so stores are coalesced float4 in [B][C][H][W].
// ---------------------------------------------------------------------------
__global__ __launch_bounds__(256) void gemm_out(
        const float* __restrict__ weighted, const float* __restrict__ Wo,
        const float* __restrict__ bo, const float* __restrict__ x,
        float* __restrict__ out) {
    __shared__ float As[32][68];   // [k][o]
    __shared__ float Bs[32][68];   // [k][p]
    const int b  = blockIdx.z;
    const int o0 = blockIdx.y * 64;
    const int p0 = blockIdx.x * 64;
    const int t  = threadIdx.x;
    const int tx = t & 15;   // p-group: p = p0 + tx*4 + j
    const int ty = t >> 4;   // o-group: o = o0 + ty*4 + i
    float acc[4][4] = {};    // [i:o][j:p]

    for (int k0 = 0; k0 < 256; k0 += 32) {
        #pragma unroll
        for (int r = 0; r < 2; ++r) {
            int flat = t + r * 256;
            int o    = flat >> 3;
            int k4   = (flat & 7) << 2;
            float4 w4 = *(const float4*)(Wo + (size_t)(o0 + o) * 256 + k0 + k4);
            As[k4 + 0][o] = w4.x; As[k4 + 1][o] = w4.y;
            As[k4 + 2][o] = w4.z; As[k4 + 3][o] = w4.w;
        }
        #pragma unroll
        for (int r = 0; r < 2; ++r) {
            int flat = t + r * 256;
            int p    = flat >> 3;            // 0..63
            int k4   = (flat & 7) << 2;      // float4 along k (contiguous in memory)
            float4 v4 = *(const float4*)(weighted + ((size_t)b * HW_ + p0 + p) * C_ + k0 + k4);
            Bs[k4 + 0][p] = v4.x; Bs[k4 + 1][p] = v4.y;
            Bs[k4 + 2][p] = v4.z; Bs[k4 + 3][p] = v4.w;
        }
        __syncthreads();
        #pragma unroll
        for (int kk = 0; kk < 32; ++kk) {
            float4 av = *(const float4*)(&As[kk][ty * 4]);
            float4 bv4 = *(const float4*)(&Bs[kk][tx * 4]);
            float aa[4] = {av.x, av.y, av.z, av.w};
            float bb[4] = {bv4.x, bv4.y, bv4.z, bv4.w};
            #pragma unroll
            for (int i = 0; i < 4; ++i)
                #pragma unroll
                for (int j = 0; j < 4; ++j)
                    acc[i][j] += aa[i] * bb[j];
        }
        __syncthreads();
    }

    #pragma unroll
    for (int i = 0; i < 4; ++i) {
        int o = o0 + ty * 4 + i;
        size_t base = ((size_t)b * C_ + o) * HW_ + p0 + tx * 4;
        float4 xr = *(const float4*)(x + base);
        float bias = bo[o];
        float4 r;
        r.x = acc[i][0] + bias + xr.x;
        r.y = acc[i][1] + bias + xr.y;
        r.z = acc[i][2] + bias + xr.z;
        r.w = acc[i][3] + bias + xr.w;
        *(float4*)(out + base) = r;
    }
}

// ---------------------------------------------------------------------------
// Launch
// ---------------------------------------------------------------------------
extern "C" void kernel_launch(void* const* d_in, const int* in_sizes, int n_in,
                              void* d_out, int out_size, void* d_ws, size_t ws_size,
                              hipStream_t stream) {
    const float* x    = (const float*)d_in[0];
    const float* Wv   = (const float*)d_in[1];
    const float* bv   = (const float*)d_in[2];
    const float* Woff = (const float*)d_in[3];
    const float* boff = (const float*)d_in[4];
    const float* Wa   = (const float*)d_in[5];
    const float* ba   = (const float*)d_in[6];
    const float* Wo   = (const float*)d_in[7];
    const float* bo   = (const float*)d_in[8];
    float* out = (float*)d_out;
    float* ws  = (float*)d_ws;

    // Workspace layout (floats):
    //   Wcat:     384*256          =    98304
    //   bcat:     384              =      384
    //   proj:     8*6400*352      = 18022400   (pixel-major [b][p][352])
    //   weighted: 8*6400*256      = 13107200   (pixel-major [b][p][256])
    // total ~124.9 MB
    float* Wcat     = ws;
    float* bcat     = ws + 98304;
    float* proj     = ws + 98688;
    float* weighted = proj + (size_t)B_ * HW_ * MPROJ;

    prep_wcat<<<dim3(MPAD), dim3(256), 0, stream>>>(Wv, bv, Woff, boff, Wa, ba, Wcat, bcat);
    gemm_proj<<<dim3(HW_ / 64, MPAD / 64, B_), dim3(256), 0, stream>>>(x, Wcat, bcat, proj);
    sample_kern<<<dim3(HW_ / 8, NH_, B_), dim3(256), 0, stream>>>(proj, weighted);
    gemm_out<<<dim3(HW_ / 64, C_ / 64, B_), dim3(256), 0, stream>>>(weighted, Wo, bo, x, out);
}

// Round 2
// 272.258 us; speedup vs baseline: 1.5392x; 1.5392x over previous
//
#include <hip/hip_runtime.h>
#include <cstddef>
#include <cstdint>

// Problem constants
#define B_    8
#define C_    256
#define Himg  80
#define Wimg  80
#define HW_   6400
#define NH_   8
#define NP_   4
#define CPH_  32
#define MPROJ 352   // 256 value + 64 offsets + 32 attn
#define MPAD  384   // padded to multiple of 128 for tiling

// ---------------------------------------------------------------------------
// Kernel 0: build concatenated weight matrix Wcat[384][256] and bias bcat[384]
// ---------------------------------------------------------------------------
__global__ __launch_bounds__(256) void prep_wcat(
        const float* __restrict__ Wv,  const float* __restrict__ bv,
        const float* __restrict__ Woff, const float* __restrict__ boff,
        const float* __restrict__ Wa,  const float* __restrict__ ba,
        float* __restrict__ Wcat, float* __restrict__ bcat) {
    int o = blockIdx.x;          // 0..383
    int t = threadIdx.x;         // 0..255
    const float* src = nullptr;
    float bias = 0.f;
    if (o < 256)       { src = Wv   + (size_t)o * 256;         bias = bv[o];         }
    else if (o < 320)  { src = Woff + (size_t)(o - 256) * 256; bias = boff[o - 256]; }
    else if (o < 352)  { src = Wa   + (size_t)(o - 320) * 256; bias = ba[o - 320];   }
    Wcat[(size_t)o * 256 + t] = src ? src[t] : 0.f;
    if (t == 0) bcat[o] = bias;
}

// ---------------------------------------------------------------------------
// Kernel 1: projection GEMM, 128x128 tile, BK=32, 8x8 micro-tile.
// proj[(b*HW + p)*352 + o] = sum_k Wcat[o][k] * x[b][k][p] + bcat[o]
// XCD swizzle: work w=((b*50+pt)*3+m); XCD k gets w in [150k,150k+150) = batch k.
// ---------------------------------------------------------------------------
__global__ __launch_bounds__(256) void gemm_proj(
        const float* __restrict__ x, const float* __restrict__ Wcat,
        const float* __restrict__ bcat, float* __restrict__ proj) {
    __shared__ float As[32][132];   // [k][o]
    __shared__ float Bs[32][132];   // [k][p]
    const int n  = blockIdx.x;            // 0..1199
    const int w  = (n & 7) * 150 + (n >> 3);
    const int m  = w % 3;
    const int bp = w / 3;                 // 0..399
    const int b  = bp / 50;
    const int pt = bp % 50;
    const int o0 = m * 128;
    const int p0 = pt * 128;
    const int t  = threadIdx.x;
    const int tx = t & 15;   // o-group
    const int ty = t >> 4;   // p-group
    const float* xb = x + (size_t)b * C_ * HW_;
    float acc[8][8] = {};    // [i:p][j:o]

    for (int k0 = 0; k0 < 256; k0 += 32) {
        #pragma unroll
        for (int r = 0; r < 4; ++r) {
            int idx = t + r * 256;           // 0..1023
            int o   = idx >> 3;              // 0..127
            int kq  = (idx & 7) << 2;        // 0..28
            float4 w4 = *(const float4*)(Wcat + (size_t)(o0 + o) * 256 + k0 + kq);
            As[kq + 0][o] = w4.x; As[kq + 1][o] = w4.y;
            As[kq + 2][o] = w4.z; As[kq + 3][o] = w4.w;
        }
        #pragma unroll
        for (int r = 0; r < 4; ++r) {
            int idx = t + r * 256;
            int k   = idx >> 5;              // 0..31
            int p4  = (idx & 31) << 2;       // 0..124
            *(float4*)(&Bs[k][p4]) =
                *(const float4*)(xb + (size_t)(k0 + k) * HW_ + p0 + p4);
        }
        __syncthreads();
        #pragma unroll
        for (int kk = 0; kk < 32; ++kk) {
            float4 a0 = *(const float4*)(&As[kk][tx * 4]);
            float4 a1 = *(const float4*)(&As[kk][tx * 4 + 64]);
            float4 b0 = *(const float4*)(&Bs[kk][ty * 4]);
            float4 b1 = *(const float4*)(&Bs[kk][ty * 4 + 64]);
            float av[8] = {a0.x,a0.y,a0.z,a0.w,a1.x,a1.y,a1.z,a1.w};
            float bv8[8] = {b0.x,b0.y,b0.z,b0.w,b1.x,b1.y,b1.z,b1.w};
            #pragma unroll
            for (int i = 0; i < 8; ++i)
                #pragma unroll
                for (int jj = 0; jj < 8; ++jj)
                    acc[i][jj] += bv8[i] * av[jj];
        }
        __syncthreads();
    }

    // biases for the two o-chunks
    int oc0 = o0 + tx * 4;
    int oc1 = o0 + tx * 4 + 64;
    float4 bias0 = (oc0 < MPROJ) ? *(const float4*)(bcat + oc0) : make_float4(0,0,0,0);
    float4 bias1 = (oc1 < MPROJ) ? *(const float4*)(bcat + oc1) : make_float4(0,0,0,0);

    #pragma unroll
    for (int i = 0; i < 8; ++i) {
        int p = p0 + ty * 4 + (i & 3) + (i >> 2) * 64;
        float* dst = proj + ((size_t)b * HW_ + p) * MPROJ;
        if (oc0 < MPROJ) {
            float4 r;
            r.x = acc[i][0] + bias0.x; r.y = acc[i][1] + bias0.y;
            r.z = acc[i][2] + bias0.z; r.w = acc[i][3] + bias0.w;
            *(float4*)(dst + oc0) = r;
        }
        if (oc1 < MPROJ) {
            float4 r;
            r.x = acc[i][4] + bias1.x; r.y = acc[i][5] + bias1.y;
            r.z = acc[i][6] + bias1.z; r.w = acc[i][7] + bias1.w;
            *(float4*)(dst + oc1) = r;
        }
    }
}

// ---------------------------------------------------------------------------
// Kernel 2: softmax + bilinear sampling + point-weighted sum.
// One wave per pixel: lane = h*8 + j; lane handles channels 4j..4j+3 of head h.
// Block = 256 threads = 4 pixels. Grid = 12800, swizzled so XCD k = batch k.
// ---------------------------------------------------------------------------
__global__ __launch_bounds__(256) void sample_kern(
        const float* __restrict__ proj, float* __restrict__ weighted) {
    const int t    = threadIdx.x;
    const int wv   = t >> 6;
    const int lane = t & 63;
    const int h    = lane >> 3;
    const int j    = lane & 7;
    const int orig = blockIdx.x;          // 0..12799
    const int b    = orig & 7;            // XCD affinity: b == orig%8
    const int p    = (orig >> 3) * 4 + wv;
    const int yy   = p / Wimg;
    const int xx   = p - yy * Wimg;

    const float* projb = proj + (size_t)b * HW_ * MPROJ;
    const float* row   = projb + (size_t)p * MPROJ;

    // softmax over the 4 points of head h
    float4 lg = *(const float4*)(row + 320 + h * 4);
    float mx  = fmaxf(fmaxf(lg.x, lg.y), fmaxf(lg.z, lg.w));
    float e0 = __expf(lg.x - mx), e1 = __expf(lg.y - mx);
    float e2 = __expf(lg.z - mx), e3 = __expf(lg.w - mx);
    float inv = 1.f / (e0 + e1 + e2 + e3);
    float wgt[4] = {e0 * inv, e1 * inv, e2 * inv, e3 * inv};

    // offsets for head h: [(x,y) pt0, (x,y) pt1], [(x,y) pt2, (x,y) pt3]
    float4 offA = *(const float4*)(row + 256 + h * 8);
    float4 offB = *(const float4*)(row + 256 + h * 8 + 4);
    float ox[4] = {offA.x, offA.z, offB.x, offB.z};
    float oy[4] = {offA.y, offA.w, offB.y, offB.w};

    const float* vb = projb + h * CPH_ + j * 4;

    float4 acc = make_float4(0.f, 0.f, 0.f, 0.f);
    #pragma unroll
    for (int pt = 0; pt < NP_; ++pt) {
        float ix = (float)xx + ox[pt] * 39.5f;
        float iy = (float)yy + oy[pt] * 39.5f;
        float x0f = floorf(ix), y0f = floorf(iy);
        int   x0  = (int)x0f,   y0  = (int)y0f;
        float wx1 = ix - x0f, wx0 = 1.f - wx1;
        float wy1 = iy - y0f, wy0 = 1.f - wy1;
        int x0c = min(max(x0, 0), Wimg - 1), x1c = min(max(x0 + 1, 0), Wimg - 1);
        int y0c = min(max(y0, 0), Himg - 1), y1c = min(max(y0 + 1, 0), Himg - 1);
        float vx0 = (x0 >= 0 && x0 <= Wimg - 1)         ? wx0 : 0.f;
        float vx1 = (x0 + 1 >= 0 && x0 + 1 <= Wimg - 1) ? wx1 : 0.f;
        float vy0 = (y0 >= 0 && y0 <= Himg - 1)         ? wy0 : 0.f;
        float vy1 = (y0 + 1 >= 0 && y0 + 1 <= Himg - 1) ? wy1 : 0.f;
        const float* r0 = vb + (size_t)(y0c * Wimg) * MPROJ;
        const float* r1 = vb + (size_t)(y1c * Wimg) * MPROJ;
        float4 v00 = *(const float4*)(r0 + (size_t)x0c * MPROJ);
        float4 v01 = *(const float4*)(r0 + (size_t)x1c * MPROJ);
        float4 v10 = *(const float4*)(r1 + (size_t)x0c * MPROJ);
        float4 v11 = *(const float4*)(r1 + (size_t)x1c * MPROJ);
        float w00 = vy0 * vx0 * wgt[pt], w01 = vy0 * vx1 * wgt[pt];
        float w10 = vy1 * vx0 * wgt[pt], w11 = vy1 * vx1 * wgt[pt];
        acc.x += w00 * v00.x + w01 * v01.x + w10 * v10.x + w11 * v11.x;
        acc.y += w00 * v00.y + w01 * v01.y + w10 * v10.y + w11 * v11.y;
        acc.z += w00 * v00.z + w01 * v01.z + w10 * v10.z + w11 * v11.z;
        acc.w += w00 * v00.w + w01 * v01.w + w10 * v10.w + w11 * v11.w;
    }
    *(float4*)(weighted + ((size_t)b * HW_ + p) * C_ + h * CPH_ + j * 4) = acc;
}

// ---------------------------------------------------------------------------
// Kernel 3: output GEMM + bias + residual, 128x128 tile, BK=32, 8x8 micro.
// out[b][o][p] = sum_k Wo[o][k] * weighted[(b*HW+p)*256 + k] + bo[o] + x[b][o][p]
// ---------------------------------------------------------------------------
__global__ __launch_bounds__(256) void gemm_out(
        const float* __restrict__ weighted, const float* __restrict__ Wo,
        const float* __restrict__ bo, const float* __restrict__ x,
        float* __restrict__ out) {
    __shared__ float As[32][132];   // [k][o]
    __shared__ float Bs[32][132];   // [k][p]
    const int n  = blockIdx.x;            // 0..799
    const int w  = (n & 7) * 100 + (n >> 3);
    const int m  = w % 2;
    const int bp = w / 2;                 // 0..399
    const int b  = bp / 50;
    const int pt = bp % 50;
    const int o0 = m * 128;
    const int p0 = pt * 128;
    const int t  = threadIdx.x;
    const int tx = t & 15;   // p-group
    const int ty = t >> 4;   // o-group
    float acc[8][8] = {};    // [i:o][j:p]

    for (int k0 = 0; k0 < 256; k0 += 32) {
        #pragma unroll
        for (int r = 0; r < 4; ++r) {
            int idx = t + r * 256;
            int o   = idx >> 3;
            int kq  = (idx & 7) << 2;
            float4 w4 = *(const float4*)(Wo + (size_t)(o0 + o) * 256 + k0 + kq);
            As[kq + 0][o] = w4.x; As[kq + 1][o] = w4.y;
            As[kq + 2][o] = w4.z; As[kq + 3][o] = w4.w;
        }
        #pragma unroll
        for (int r = 0; r < 4; ++r) {
            int idx = t + r * 256;
            int p   = idx >> 3;              // 0..127
            int kq  = (idx & 7) << 2;
            float4 v4 = *(const float4*)(weighted + ((size_t)b * HW_ + p0 + p) * C_ + k0 + kq);
            Bs[kq + 0][p] = v4.x; Bs[kq + 1][p] = v4.y;
            Bs[kq + 2][p] = v4.z; Bs[kq + 3][p] = v4.w;
        }
        __syncthreads();
        #pragma unroll
        for (int kk = 0; kk < 32; ++kk) {
            float4 a0 = *(const float4*)(&As[kk][ty * 4]);
            float4 a1 = *(const float4*)(&As[kk][ty * 4 + 64]);
            float4 b0 = *(const float4*)(&Bs[kk][tx * 4]);
            float4 b1 = *(const float4*)(&Bs[kk][tx * 4 + 64]);
            float av[8] = {a0.x,a0.y,a0.z,a0.w,a1.x,a1.y,a1.z,a1.w};
            float bv8[8] = {b0.x,b0.y,b0.z,b0.w,b1.x,b1.y,b1.z,b1.w};
            #pragma unroll
            for (int i = 0; i < 8; ++i)
                #pragma unroll
                for (int jj = 0; jj < 8; ++jj)
                    acc[i][jj] += av[i] * bv8[jj];
        }
        __syncthreads();
    }

    #pragma unroll
    for (int i = 0; i < 8; ++i) {
        int o = o0 + ty * 4 + (i & 3) + (i >> 2) * 64;
        float bias = bo[o];
        #pragma unroll
        for (int c = 0; c < 2; ++c) {
            size_t base = ((size_t)b * C_ + o) * HW_ + p0 + tx * 4 + c * 64;
            float4 xr = *(const float4*)(x + base);
            float4 r;
            r.x = acc[i][c*4+0] + bias + xr.x;
            r.y = acc[i][c*4+1] + bias + xr.y;
            r.z = acc[i][c*4+2] + bias + xr.z;
            r.w = acc[i][c*4+3] + bias + xr.w;
            *(float4*)(out + base) = r;
        }
    }
}

// ---------------------------------------------------------------------------
// Launch
// ---------------------------------------------------------------------------
extern "C" void kernel_launch(void* const* d_in, const int* in_sizes, int n_in,
                              void* d_out, int out_size, void* d_ws, size_t ws_size,
                              hipStream_t stream) {
    const float* x    = (const float*)d_in[0];
    const float* Wv   = (const float*)d_in[1];
    const float* bv   = (const float*)d_in[2];
    const float* Woff = (const float*)d_in[3];
    const float* boff = (const float*)d_in[4];
    const float* Wa   = (const float*)d_in[5];
    const float* ba   = (const float*)d_in[6];
    const float* Wo   = (const float*)d_in[7];
    const float* bo   = (const float*)d_in[8];
    float* out = (float*)d_out;
    float* ws  = (float*)d_ws;

    float* Wcat     = ws;
    float* bcat     = ws + 98304;
    float* proj     = ws + 98688;
    float* weighted = proj + (size_t)B_ * HW_ * MPROJ;

    prep_wcat<<<dim3(MPAD), dim3(256), 0, stream>>>(Wv, bv, Woff, boff, Wa, ba, Wcat, bcat);
    gemm_proj<<<dim3(1200), dim3(256), 0, stream>>>(x, Wcat, bcat, proj);
    sample_kern<<<dim3(12800), dim3(256), 0, stream>>>(proj, weighted);
    gemm_out<<<dim3(800), dim3(256), 0, stream>>>(weighted, Wo, bo, x, out);
}

// Round 3
// 132.804 us; speedup vs baseline: 3.1555x; 2.0501x over previous
//
#include <hip/hip_runtime.h>
#include <cstddef>
#include <cstdint>

#define B_    8
#define C_    256
#define Himg  80
#define Wimg  80
#define HW_   6400
#define NH_   8
#define NP_   4
#define MPROJ 352

using bf16x8 = __attribute__((ext_vector_type(8))) short;
using f32x4  = __attribute__((ext_vector_type(4))) float;

__device__ __forceinline__ unsigned short f2bf(float f) {
    union { float f; uint32_t u; } v; v.f = f;
    uint32_t r = v.u + 0x7FFFu + ((v.u >> 16) & 1u);
    return (unsigned short)(r >> 16);
}
__device__ __forceinline__ float bf2f(unsigned short s) {
    union { uint32_t u; float f; } v; v.u = ((uint32_t)s) << 16;
    return v.f;
}

#define GLD16(gsrc, ldst) \
    __builtin_amdgcn_global_load_lds( \
        (const __attribute__((address_space(1))) unsigned int*)(gsrc), \
        (__attribute__((address_space(3))) unsigned int*)(ldst), 16, 0, 0)

// ---------------------------------------------------------------------------
// Kernel 0: weights -> bf16. Blocks 0..383: Wcat row (Wv/Woff/Wa, zero-pad) +
// bcat; blocks 384..639: Wo row.
// ---------------------------------------------------------------------------
__global__ __launch_bounds__(256) void prep_w(
        const float* __restrict__ Wv,  const float* __restrict__ bv,
        const float* __restrict__ Woff, const float* __restrict__ boff,
        const float* __restrict__ Wa,  const float* __restrict__ ba,
        const float* __restrict__ Wo,
        short* __restrict__ WcatBf, short* __restrict__ WoBf,
        float* __restrict__ bcat) {
    int o = blockIdx.x, t = threadIdx.x;
    if (o < 384) {
        const float* src = nullptr; float bias = 0.f;
        if (o < 256)      { src = Wv   + (size_t)o * 256;         bias = bv[o];         }
        else if (o < 320) { src = Woff + (size_t)(o - 256) * 256; bias = boff[o - 256]; }
        else if (o < 352) { src = Wa   + (size_t)(o - 320) * 256; bias = ba[o - 320];   }
        WcatBf[(size_t)o * 256 + t] = src ? (short)f2bf(src[t]) : (short)0;
        if (t == 0) bcat[o] = bias;
    } else {
        int oo = o - 384;
        WoBf[(size_t)oo * 256 + t] = (short)f2bf(Wo[(size_t)oo * 256 + t]);
    }
}

// ---------------------------------------------------------------------------
// Kernel 1: transpose+convert  x[b][k][p] f32 -> xT[b][p][k] bf16.
// Tile 64k x 64p per block. Grid (100, 4, 8).
// ---------------------------------------------------------------------------
__global__ __launch_bounds__(256) void transpose_x(
        const float* __restrict__ x, short* __restrict__ xT) {
    __shared__ float tile[64][68];
    const int b = blockIdx.z, k0 = blockIdx.y * 64, p0 = blockIdx.x * 64;
    const int t = threadIdx.x;
    const float* xb = x + ((size_t)b * C_ + k0) * HW_ + p0;
    #pragma unroll
    for (int r = 0; r < 4; ++r) {
        int kk = r * 16 + (t >> 4);
        int pp = (t & 15) * 4;
        float4 v = *(const float4*)(xb + (size_t)kk * HW_ + pp);
        *(float4*)&tile[kk][pp] = v;
    }
    __syncthreads();
    const int pp = t >> 2, kc = (t & 3) * 16;
    short tmp[16];
    #pragma unroll
    for (int i = 0; i < 16; ++i) tmp[i] = (short)f2bf(tile[kc + i][pp]);
    short* dst = xT + ((size_t)b * HW_ + p0 + pp) * 256 + k0 + kc;
    *(bf16x8*)dst       = *(bf16x8*)tmp;
    *(bf16x8*)(dst + 8) = *(bf16x8*)(tmp + 8);
}

// ---------------------------------------------------------------------------
// Shared MFMA GEMM body: 128(M=o) x 128(N=p) tile, BK=64, 4 waves (2x2),
// 4x4 16x16x32 fragments per wave. LDS linear dest + inverse-swizzled global
// source; fragment reads XOR-swizzled (byte chunk ^= row&7).
// ---------------------------------------------------------------------------
#define GEMM_STAGE(Asrc, Bsrc)                                                  \
    _Pragma("unroll")                                                           \
    for (int q = 0; q < 4; ++q) {                                               \
        int i = wid * 4 + q;                                                    \
        int row = i * 8 + (lane >> 3);                                          \
        int sc  = (lane & 7) ^ (row & 7);                                       \
        GLD16((Asrc) + (size_t)(o0 + row) * 256 + k0 + sc * 8, &lA[i * 512]);   \
        GLD16((Bsrc) + (size_t)(p0 + row) * 256 + k0 + sc * 8, &lB[i * 512]);   \
    }

#define GEMM_COMPUTE()                                                          \
    _Pragma("unroll")                                                           \
    for (int kk = 0; kk < 2; ++kk) {                                            \
        bf16x8 af[4], bfr[4];                                                   \
        _Pragma("unroll")                                                       \
        for (int m = 0; m < 4; ++m) {                                           \
            int row = wo0 + m * 16 + (lane & 15);                               \
            int cph = (kk * 4 + (lane >> 4)) ^ (row & 7);                       \
            af[m] = *(const bf16x8*)&lA[row * 64 + cph * 8];                    \
        }                                                                       \
        _Pragma("unroll")                                                       \
        for (int nn = 0; nn < 4; ++nn) {                                        \
            int row = wp0 + nn * 16 + (lane & 15);                              \
            int cph = (kk * 4 + (lane >> 4)) ^ (row & 7);                       \
            bfr[nn] = *(const bf16x8*)&lB[row * 64 + cph * 8];                  \
        }                                                                       \
        _Pragma("unroll")                                                       \
        for (int m = 0; m < 4; ++m)                                             \
            _Pragma("unroll")                                                   \
            for (int nn = 0; nn < 4; ++nn)                                      \
                acc[m][nn] = __builtin_amdgcn_mfma_f32_16x16x32_bf16(           \
                    af[m], bfr[nn], acc[m][nn], 0, 0, 0);                       \
    }

// ---------------------------------------------------------------------------
// Kernel 2: projection GEMM. A=WcatBf[384][256], B=xT[b][p][256].
// Output: o<256 -> val bf16 [b][p][256];  256<=o<352 -> meta f32 [b][p][96].
// Grid 1200, XCD swizzle: batch = blockIdx.x & 7.
// ---------------------------------------------------------------------------
__global__ __launch_bounds__(256) void gemm_proj_mfma(
        const short* __restrict__ Wb, const float* __restrict__ bcat,
        const short* __restrict__ xT,
        short* __restrict__ val, float* __restrict__ meta) {
    __shared__ short lA[128 * 64];
    __shared__ short lB[128 * 64];
    const int n = blockIdx.x;
    const int w = (n & 7) * 150 + (n >> 3);
    const int b = w / 150;
    const int r150 = w % 150;
    const int o0 = (r150 / 50) * 128;
    const int p0 = (r150 % 50) * 128;
    const int t = threadIdx.x;
    const int wid = t >> 6, lane = t & 63;
    const int wo0 = (wid & 1) * 64, wp0 = (wid >> 1) * 64;
    const short* xTb = xT + (size_t)b * HW_ * 256;
    f32x4 acc[4][4] = {};

    for (int k0 = 0; k0 < 256; k0 += 64) {
        GEMM_STAGE(Wb, xTb)
        __syncthreads();
        GEMM_COMPUTE()
        __syncthreads();
    }

    #pragma unroll
    for (int m = 0; m < 4; ++m) {
        int oc = o0 + wo0 + m * 16 + (lane >> 4) * 4;
        if (oc >= MPROJ) continue;
        float4 bias = *(const float4*)(bcat + oc);
        #pragma unroll
        for (int nn = 0; nn < 4; ++nn) {
            int p = p0 + wp0 + nn * 16 + (lane & 15);
            f32x4 a = acc[m][nn];
            float v0 = a[0] + bias.x, v1 = a[1] + bias.y;
            float v2 = a[2] + bias.z, v3 = a[3] + bias.w;
            if (oc < 256) {
                ushort4 u;
                u.x = f2bf(v0); u.y = f2bf(v1); u.z = f2bf(v2); u.w = f2bf(v3);
                *(ushort4*)(val + ((size_t)b * HW_ + p) * 256 + oc) = u;
            } else {
                float4 f; f.x = v0; f.y = v1; f.z = v2; f.w = v3;
                *(float4*)(meta + ((size_t)b * HW_ + p) * 96 + (oc - 256)) = f;
            }
        }
    }
}

// ---------------------------------------------------------------------------
// Kernel 3: softmax + bilinear sampling + point-weighted sum.
// One wave per pixel (8 heads x 8 lanes x 4 channels). bf16 values, f32 meta.
// ---------------------------------------------------------------------------
__global__ __launch_bounds__(256) void sample_kern(
        const short* __restrict__ val, const float* __restrict__ meta,
        short* __restrict__ wout) {
    const int t    = threadIdx.x;
    const int wv   = t >> 6, lane = t & 63;
    const int h    = lane >> 3, j = lane & 7;
    const int orig = blockIdx.x;
    const int b    = orig & 7;
    const int p    = (orig >> 3) * 4 + wv;
    const int yy   = p / Wimg;
    const int xx   = p - yy * Wimg;

    const float* mrow = meta + ((size_t)b * HW_ + p) * 96;
    float4 lg = *(const float4*)(mrow + 64 + h * 4);
    float mx  = fmaxf(fmaxf(lg.x, lg.y), fmaxf(lg.z, lg.w));
    float e0 = __expf(lg.x - mx), e1 = __expf(lg.y - mx);
    float e2 = __expf(lg.z - mx), e3 = __expf(lg.w - mx);
    float inv = 1.f / (e0 + e1 + e2 + e3);
    float wgt[4] = {e0 * inv, e1 * inv, e2 * inv, e3 * inv};

    float4 offA = *(const float4*)(mrow + h * 8);
    float4 offB = *(const float4*)(mrow + h * 8 + 4);
    float ox[4] = {offA.x, offA.z, offB.x, offB.z};
    float oy[4] = {offA.y, offA.w, offB.y, offB.w};

    const short* vb = val + (size_t)b * HW_ * 256 + h * 32 + j * 4;

    float4 acc = make_float4(0.f, 0.f, 0.f, 0.f);
    #pragma unroll
    for (int pt = 0; pt < NP_; ++pt) {
        float ix = (float)xx + ox[pt] * 39.5f;
        float iy = (float)yy + oy[pt] * 39.5f;
        float x0f = floorf(ix), y0f = floorf(iy);
        int   x0  = (int)x0f,   y0  = (int)y0f;
        float wx1 = ix - x0f, wx0 = 1.f - wx1;
        float wy1 = iy - y0f, wy0 = 1.f - wy1;
        int x0c = min(max(x0, 0), Wimg - 1), x1c = min(max(x0 + 1, 0), Wimg - 1);
        int y0c = min(max(y0, 0), Himg - 1), y1c = min(max(y0 + 1, 0), Himg - 1);
        float vx0 = (x0 >= 0 && x0 <= Wimg - 1)         ? wx0 : 0.f;
        float vx1 = (x0 + 1 >= 0 && x0 + 1 <= Wimg - 1) ? wx1 : 0.f;
        float vy0 = (y0 >= 0 && y0 <= Himg - 1)         ? wy0 : 0.f;
        float vy1 = (y0 + 1 >= 0 && y0 + 1 <= Himg - 1) ? wy1 : 0.f;
        const short* r0 = vb + (size_t)(y0c * Wimg) * 256;
        const short* r1 = vb + (size_t)(y1c * Wimg) * 256;
        ushort4 u00 = *(const ushort4*)(r0 + (size_t)x0c * 256);
        ushort4 u01 = *(const ushort4*)(r0 + (size_t)x1c * 256);
        ushort4 u10 = *(const ushort4*)(r1 + (size_t)x0c * 256);
        ushort4 u11 = *(const ushort4*)(r1 + (size_t)x1c * 256);
        float w00 = vy0 * vx0 * wgt[pt], w01 = vy0 * vx1 * wgt[pt];
        float w10 = vy1 * vx0 * wgt[pt], w11 = vy1 * vx1 * wgt[pt];
        acc.x += w00 * bf2f(u00.x) + w01 * bf2f(u01.x) + w10 * bf2f(u10.x) + w11 * bf2f(u11.x);
        acc.y += w00 * bf2f(u00.y) + w01 * bf2f(u01.y) + w10 * bf2f(u10.y) + w11 * bf2f(u11.y);
        acc.z += w00 * bf2f(u00.z) + w01 * bf2f(u01.z) + w10 * bf2f(u10.z) + w11 * bf2f(u11.z);
        acc.w += w00 * bf2f(u00.w) + w01 * bf2f(u01.w) + w10 * bf2f(u10.w) + w11 * bf2f(u11.w);
    }
    ushort4 o;
    o.x = f2bf(acc.x); o.y = f2bf(acc.y); o.z = f2bf(acc.z); o.w = f2bf(acc.w);
    *(ushort4*)(wout + ((size_t)b * HW_ + p) * 256 + h * 32 + j * 4) = o;
}

// ---------------------------------------------------------------------------
// Kernel 4: output GEMM + bias + residual. A=WoBf[256][256], B=wout[b][p][256].
// out[b][o][p] f32. Grid 800, XCD swizzle.
// ---------------------------------------------------------------------------
__global__ __launch_bounds__(256) void gemm_out_mfma(
        const short* __restrict__ Wb, const float* __restrict__ bo,
        const short* __restrict__ wgt, const float* __restrict__ x,
        float* __restrict__ out) {
    __shared__ short lA[128 * 64];
    __shared__ short lB[128 * 64];
    const int n = blockIdx.x;
    const int w = (n & 7) * 100 + (n >> 3);
    const int b = w / 100;
    const int r100 = w % 100;
    const int o0 = (r100 / 50) * 128;
    const int p0 = (r100 % 50) * 128;
    const int t = threadIdx.x;
    const int wid = t >> 6, lane = t & 63;
    const int wo0 = (wid & 1) * 64, wp0 = (wid >> 1) * 64;
    const short* wgtb = wgt + (size_t)b * HW_ * 256;
    f32x4 acc[4][4] = {};

    for (int k0 = 0; k0 < 256; k0 += 64) {
        GEMM_STAGE(Wb, wgtb)
        __syncthreads();
        GEMM_COMPUTE()
        __syncthreads();
    }

    #pragma unroll
    for (int m = 0; m < 4; ++m) {
        int oc = o0 + wo0 + m * 16 + (lane >> 4) * 4;
        float4 bias = *(const float4*)(bo + oc);
        float br[4] = {bias.x, bias.y, bias.z, bias.w};
        #pragma unroll
        for (int nn = 0; nn < 4; ++nn) {
            int p = p0 + wp0 + nn * 16 + (lane & 15);
            f32x4 a = acc[m][nn];
            #pragma unroll
            for (int reg = 0; reg < 4; ++reg) {
                size_t ad = ((size_t)b * C_ + oc + reg) * HW_ + p;
                out[ad] = a[reg] + br[reg] + x[ad];
            }
        }
    }
}

// ---------------------------------------------------------------------------
// Launch
// ---------------------------------------------------------------------------
extern "C" void kernel_launch(void* const* d_in, const int* in_sizes, int n_in,
                              void* d_out, int out_size, void* d_ws, size_t ws_size,
                              hipStream_t stream) {
    const float* x    = (const float*)d_in[0];
    const float* Wv   = (const float*)d_in[1];
    const float* bv   = (const float*)d_in[2];
    const float* Woff = (const float*)d_in[3];
    const float* boff = (const float*)d_in[4];
    const float* Wa   = (const float*)d_in[5];
    const float* ba   = (const float*)d_in[6];
    const float* Wo   = (const float*)d_in[7];
    const float* bo   = (const float*)d_in[8];
    float* out = (float*)d_out;
    char* base = (char*)d_ws;

    // Workspace carve (bytes, 256-aligned):
    short* WcatBf = (short*)(base);               //   196608
    short* WoBf   = (short*)(base + 196608);      //   131072
    float* bcat   = (float*)(base + 327680);      //     1536 (+pad)
    short* xT     = (short*)(base + 329728);      // 26214400
    short* val    = (short*)(base + 26544128);    // 26214400
    float* meta   = (float*)(base + 52758528);    // 19660800
    short* wbuf   = (short*)(base + 72419328);    // 26214400  -> total ~98.6 MB

    prep_w<<<dim3(640), dim3(256), 0, stream>>>(Wv, bv, Woff, boff, Wa, ba, Wo,
                                                WcatBf, WoBf, bcat);
    transpose_x<<<dim3(100, 4, 8), dim3(256), 0, stream>>>(x, xT);
    gemm_proj_mfma<<<dim3(1200), dim3(256), 0, stream>>>(WcatBf, bcat, xT, val, meta);
    sample_kern<<<dim3(12800), dim3(256), 0, stream>>>(val, meta, wbuf);
    gemm_out_mfma<<<dim3(800), dim3(256), 0, stream>>>(WoBf, bo, wbuf, x, out);
}

// Round 4
// 109.392 us; speedup vs baseline: 3.8308x; 1.2140x over previous
//
#include <hip/hip_runtime.h>
#include <cstddef>
#include <cstdint>

#define B_    8
#define C_    256
#define Himg  80
#define Wimg  80
#define HW_   6400
#define NH_   8
#define NP_   4
#define MPROJ 352

using bf16x8 = __attribute__((ext_vector_type(8))) short;
using f32x4  = __attribute__((ext_vector_type(4))) float;

__device__ __forceinline__ unsigned short f2bf(float f) {
    union { float f; uint32_t u; } v; v.f = f;
    uint32_t r = v.u + 0x7FFFu + ((v.u >> 16) & 1u);
    return (unsigned short)(r >> 16);
}
__device__ __forceinline__ float bf2f(unsigned short s) {
    union { uint32_t u; float f; } v; v.u = ((uint32_t)s) << 16;
    return v.f;
}

#define GLD16(gsrc, ldst) \
    __builtin_amdgcn_global_load_lds( \
        (const __attribute__((address_space(1))) unsigned int*)(gsrc), \
        (__attribute__((address_space(3))) unsigned int*)(ldst), 16, 0, 0)

// ---------------------------------------------------------------------------
// Kernel 0: weights -> bf16.
// ---------------------------------------------------------------------------
__global__ __launch_bounds__(256) void prep_w(
        const float* __restrict__ Wv,  const float* __restrict__ bv,
        const float* __restrict__ Woff, const float* __restrict__ boff,
        const float* __restrict__ Wa,  const float* __restrict__ ba,
        const float* __restrict__ Wo,
        short* __restrict__ WcatBf, short* __restrict__ WoBf,
        float* __restrict__ bcat) {
    int o = blockIdx.x, t = threadIdx.x;
    if (o < 384) {
        const float* src = nullptr; float bias = 0.f;
        if (o < 256)      { src = Wv   + (size_t)o * 256;         bias = bv[o];         }
        else if (o < 320) { src = Woff + (size_t)(o - 256) * 256; bias = boff[o - 256]; }
        else if (o < 352) { src = Wa   + (size_t)(o - 320) * 256; bias = ba[o - 320];   }
        WcatBf[(size_t)o * 256 + t] = src ? (short)f2bf(src[t]) : (short)0;
        if (t == 0) bcat[o] = bias;
    } else {
        int oo = o - 384;
        WoBf[(size_t)oo * 256 + t] = (short)f2bf(Wo[(size_t)oo * 256 + t]);
    }
}

// ---------------------------------------------------------------------------
// Kernel 1: transpose+convert  x[b][k][p] f32 -> xT[b][p][k] bf16.
// ---------------------------------------------------------------------------
__global__ __launch_bounds__(256) void transpose_x(
        const float* __restrict__ x, short* __restrict__ xT) {
    __shared__ float tile[64][68];
    const int b = blockIdx.z, k0 = blockIdx.y * 64, p0 = blockIdx.x * 64;
    const int t = threadIdx.x;
    const float* xb = x + ((size_t)b * C_ + k0) * HW_ + p0;
    #pragma unroll
    for (int r = 0; r < 4; ++r) {
        int kk = r * 16 + (t >> 4);
        int pp = (t & 15) * 4;
        float4 v = *(const float4*)(xb + (size_t)kk * HW_ + pp);
        *(float4*)&tile[kk][pp] = v;
    }
    __syncthreads();
    const int pp = t >> 2, kc = (t & 3) * 16;
    short tmp[16];
    #pragma unroll
    for (int i = 0; i < 16; ++i) tmp[i] = (short)f2bf(tile[kc + i][pp]);
    short* dst = xT + ((size_t)b * HW_ + p0 + pp) * 256 + k0 + kc;
    *(bf16x8*)dst       = *(bf16x8*)tmp;
    *(bf16x8*)(dst + 8) = *(bf16x8*)(tmp + 8);
}

// ---------------------------------------------------------------------------
// Kernel 2: projection GEMM, 128(o) x 128(p), BK=64, 2-phase pipelined.
// ---------------------------------------------------------------------------
#define PSTAGE(buf, k0)                                                         \
    _Pragma("unroll")                                                           \
    for (int q = 0; q < 4; ++q) {                                               \
        int i = wid * 4 + q;                                                    \
        int row = i * 8 + (lane >> 3);                                          \
        int sc  = (lane & 7) ^ (row & 7);                                       \
        GLD16(Wb  + (size_t)(o0 + row) * 256 + (k0) + sc * 8,                   \
              &lA[(buf)][i * 512]);                                             \
        GLD16(xTb + (size_t)(p0 + row) * 256 + (k0) + sc * 8,                   \
              &lB[(buf)][i * 512]);                                             \
    }

#define PCOMPUTE(buf)                                                           \
    _Pragma("unroll")                                                           \
    for (int kk = 0; kk < 2; ++kk) {                                            \
        bf16x8 af[4], bfr[4];                                                   \
        _Pragma("unroll")                                                       \
        for (int m = 0; m < 4; ++m) {                                           \
            int row = wo0 + m * 16 + (lane & 15);                               \
            int cph = (kk * 4 + (lane >> 4)) ^ (row & 7);                       \
            af[m] = *(const bf16x8*)&lA[(buf)][row * 64 + cph * 8];             \
        }                                                                       \
        _Pragma("unroll")                                                       \
        for (int nn = 0; nn < 4; ++nn) {                                        \
            int row = wp0 + nn * 16 + (lane & 15);                              \
            int cph = (kk * 4 + (lane >> 4)) ^ (row & 7);                       \
            bfr[nn] = *(const bf16x8*)&lB[(buf)][row * 64 + cph * 8];           \
        }                                                                       \
        _Pragma("unroll")                                                       \
        for (int m = 0; m < 4; ++m)                                             \
            _Pragma("unroll")                                                   \
            for (int nn = 0; nn < 4; ++nn)                                      \
                acc[m][nn] = __builtin_amdgcn_mfma_f32_16x16x32_bf16(           \
                    af[m], bfr[nn], acc[m][nn], 0, 0, 0);                       \
    }

__global__ __launch_bounds__(256) void gemm_proj_mfma(
        const short* __restrict__ Wb, const float* __restrict__ bcat,
        const short* __restrict__ xT,
        short* __restrict__ val, float* __restrict__ meta) {
    __shared__ short lA[2][8192];
    __shared__ short lB[2][8192];
    const int n = blockIdx.x;
    const int w = (n & 7) * 150 + (n >> 3);
    const int b = w / 150;
    const int r150 = w % 150;
    const int o0 = (r150 / 50) * 128;
    const int p0 = (r150 % 50) * 128;
    const int t = threadIdx.x;
    const int wid = t >> 6, lane = t & 63;
    const int wo0 = (wid & 1) * 64, wp0 = (wid >> 1) * 64;
    const short* xTb = xT + (size_t)b * HW_ * 256;
    f32x4 acc[4][4] = {};

    PSTAGE(0, 0)
    __syncthreads();
    #pragma unroll
    for (int kt = 0; kt < 3; ++kt) {
        const int cur = kt & 1;
        PSTAGE(cur ^ 1, (kt + 1) * 64)
        PCOMPUTE(cur)
        __syncthreads();
    }
    PCOMPUTE(1)

    #pragma unroll
    for (int m = 0; m < 4; ++m) {
        int oc = o0 + wo0 + m * 16 + (lane >> 4) * 4;
        if (oc >= MPROJ) continue;
        float4 bias = *(const float4*)(bcat + oc);
        #pragma unroll
        for (int nn = 0; nn < 4; ++nn) {
            int p = p0 + wp0 + nn * 16 + (lane & 15);
            f32x4 a = acc[m][nn];
            float v0 = a[0] + bias.x, v1 = a[1] + bias.y;
            float v2 = a[2] + bias.z, v3 = a[3] + bias.w;
            if (oc < 256) {
                ushort4 u;
                u.x = f2bf(v0); u.y = f2bf(v1); u.z = f2bf(v2); u.w = f2bf(v3);
                *(ushort4*)(val + ((size_t)b * HW_ + p) * 256 + oc) = u;
            } else {
                float4 f; f.x = v0; f.y = v1; f.z = v2; f.w = v3;
                *(float4*)(meta + ((size_t)b * HW_ + p) * 96 + (oc - 256)) = f;
            }
        }
    }
}

// ---------------------------------------------------------------------------
// Kernel 3: softmax + bilinear sampling + point-weighted sum.
// Wave = 2 pixels; lane&31: h=(li>>2), j=li&3 -> channels j*8..j*8+7 (16B).
// Block = 8 pixels. Grid 6400, batch = blockIdx & 7 (XCD affinity).
// ---------------------------------------------------------------------------
__global__ __launch_bounds__(256) void sample_kern(
        const short* __restrict__ val, const float* __restrict__ meta,
        short* __restrict__ wout) {
    const int t = threadIdx.x;
    const int wid = t >> 6, lane = t & 63;
    const int sub = lane >> 5, li = lane & 31;
    const int h = li >> 2, j = li & 3;
    const int orig = blockIdx.x;
    const int b = orig & 7;
    const int p = (orig >> 3) * 8 + wid * 2 + sub;
    const int yy = p / Wimg;
    const int xx = p - yy * Wimg;

    const float* mrow = meta + ((size_t)b * HW_ + p) * 96;
    float4 lg = *(const float4*)(mrow + 64 + h * 4);
    float mx  = fmaxf(fmaxf(lg.x, lg.y), fmaxf(lg.z, lg.w));
    float e0 = __expf(lg.x - mx), e1 = __expf(lg.y - mx);
    float e2 = __expf(lg.z - mx), e3 = __expf(lg.w - mx);
    float inv = 1.f / (e0 + e1 + e2 + e3);
    float wgt[4] = {e0 * inv, e1 * inv, e2 * inv, e3 * inv};

    float4 offA = *(const float4*)(mrow + h * 8);
    float4 offB = *(const float4*)(mrow + h * 8 + 4);
    float ox[4] = {offA.x, offA.z, offB.x, offB.z};
    float oy[4] = {offA.y, offA.w, offB.y, offB.w};

    const short* vb = val + (size_t)b * HW_ * 256 + h * 32 + j * 8;

    float acc[8] = {};
    #pragma unroll
    for (int pt = 0; pt < NP_; ++pt) {
        float ix = (float)xx + ox[pt] * 39.5f;
        float iy = (float)yy + oy[pt] * 39.5f;
        float x0f = floorf(ix), y0f = floorf(iy);
        int   x0  = (int)x0f,   y0  = (int)y0f;
        float wx1 = ix - x0f, wx0 = 1.f - wx1;
        float wy1 = iy - y0f, wy0 = 1.f - wy1;
        int x0c = min(max(x0, 0), Wimg - 1), x1c = min(max(x0 + 1, 0), Wimg - 1);
        int y0c = min(max(y0, 0), Himg - 1), y1c = min(max(y0 + 1, 0), Himg - 1);
        float vx0 = (x0 >= 0 && x0 <= Wimg - 1)         ? wx0 : 0.f;
        float vx1 = (x0 + 1 >= 0 && x0 + 1 <= Wimg - 1) ? wx1 : 0.f;
        float vy0 = (y0 >= 0 && y0 <= Himg - 1)         ? wy0 : 0.f;
        float vy1 = (y0 + 1 >= 0 && y0 + 1 <= Himg - 1) ? wy1 : 0.f;
        bf16x8 u00 = *(const bf16x8*)(vb + (size_t)(y0c * Wimg + x0c) * 256);
        bf16x8 u01 = *(const bf16x8*)(vb + (size_t)(y0c * Wimg + x1c) * 256);
        bf16x8 u10 = *(const bf16x8*)(vb + (size_t)(y1c * Wimg + x0c) * 256);
        bf16x8 u11 = *(const bf16x8*)(vb + (size_t)(y1c * Wimg + x1c) * 256);
        float w00 = vy0 * vx0 * wgt[pt], w01 = vy0 * vx1 * wgt[pt];
        float w10 = vy1 * vx0 * wgt[pt], w11 = vy1 * vx1 * wgt[pt];
        #pragma unroll
        for (int c = 0; c < 8; ++c) {
            acc[c] += w00 * bf2f((unsigned short)u00[c])
                    + w01 * bf2f((unsigned short)u01[c])
                    + w10 * bf2f((unsigned short)u10[c])
                    + w11 * bf2f((unsigned short)u11[c]);
        }
    }
    short tmp[8];
    #pragma unroll
    for (int c = 0; c < 8; ++c) tmp[c] = (short)f2bf(acc[c]);
    *(bf16x8*)(wout + ((size_t)b * HW_ + p) * 256 + h * 32 + j * 8) = *(bf16x8*)tmp;
}

// ---------------------------------------------------------------------------
// Kernel 4: output GEMM + bias + residual, 64(o) x 128(p), BK=64, 2-phase.
// Grid 1600 (4 o-tiles x 50 p-tiles x 8 b), XCD swizzle.
// ---------------------------------------------------------------------------
#define OSTAGE(buf, k0)                                                         \
    _Pragma("unroll")                                                           \
    for (int q = 0; q < 2; ++q) {                                               \
        int i = wid * 2 + q;                                                    \
        int row = i * 8 + (lane >> 3);                                          \
        int sc  = (lane & 7) ^ (row & 7);                                       \
        GLD16(Wb + (size_t)(o0 + row) * 256 + (k0) + sc * 8,                    \
              &lA[(buf)][i * 512]);                                             \
    }                                                                           \
    _Pragma("unroll")                                                           \
    for (int q = 0; q < 4; ++q) {                                               \
        int i = wid * 4 + q;                                                    \
        int row = i * 8 + (lane >> 3);                                          \
        int sc  = (lane & 7) ^ (row & 7);                                       \
        GLD16(wgtb + (size_t)(p0 + row) * 256 + (k0) + sc * 8,                  \
              &lB[(buf)][i * 512]);                                             \
    }

#define OCOMPUTE(buf)                                                           \
    _Pragma("unroll")                                                           \
    for (int kk = 0; kk < 2; ++kk) {                                            \
        bf16x8 af[4], bfr[2];                                                   \
        _Pragma("unroll")                                                       \
        for (int m = 0; m < 4; ++m) {                                           \
            int row = m * 16 + (lane & 15);                                     \
            int cph = (kk * 4 + (lane >> 4)) ^ (row & 7);                       \
            af[m] = *(const bf16x8*)&lA[(buf)][row * 64 + cph * 8];             \
        }                                                                       \
        _Pragma("unroll")                                                       \
        for (int nn = 0; nn < 2; ++nn) {                                        \
            int row = wid * 32 + nn * 16 + (lane & 15);                         \
            int cph = (kk * 4 + (lane >> 4)) ^ (row & 7);                       \
            bfr[nn] = *(const bf16x8*)&lB[(buf)][row * 64 + cph * 8];           \
        }                                                                       \
        _Pragma("unroll")                                                       \
        for (int m = 0; m < 4; ++m)                                             \
            _Pragma("unroll")                                                   \
            for (int nn = 0; nn < 2; ++nn)                                      \
                acc[m][nn] = __builtin_amdgcn_mfma_f32_16x16x32_bf16(           \
                    af[m], bfr[nn], acc[m][nn], 0, 0, 0);                       \
    }

__global__ __launch_bounds__(256) void gemm_out_mfma(
        const short* __restrict__ Wb, const float* __restrict__ bo,
        const short* __restrict__ wgt, const float* __restrict__ x,
        float* __restrict__ out) {
    __shared__ short lA[2][4096];
    __shared__ short lB[2][8192];
    const int n = blockIdx.x;               // 0..1599
    const int w = (n & 7) * 200 + (n >> 3);
    const int b = w / 200;
    const int r200 = w % 200;
    const int o0 = (r200 / 50) * 64;
    const int p0 = (r200 % 50) * 128;
    const int t = threadIdx.x;
    const int wid = t >> 6, lane = t & 63;
    const short* wgtb = wgt + (size_t)b * HW_ * 256;
    f32x4 acc[4][2] = {};

    OSTAGE(0, 0)
    __syncthreads();
    #pragma unroll
    for (int kt = 0; kt < 3; ++kt) {
        const int cur = kt & 1;
        OSTAGE(cur ^ 1, (kt + 1) * 64)
        OCOMPUTE(cur)
        __syncthreads();
    }
    OCOMPUTE(1)

    #pragma unroll
    for (int m = 0; m < 4; ++m) {
        int oc = o0 + m * 16 + (lane >> 4) * 4;
        float4 bias = *(const float4*)(bo + oc);
        float br[4] = {bias.x, bias.y, bias.z, bias.w};
        #pragma unroll
        for (int nn = 0; nn < 2; ++nn) {
            int p = p0 + wid * 32 + nn * 16 + (lane & 15);
            f32x4 a = acc[m][nn];
            #pragma unroll
            for (int reg = 0; reg < 4; ++reg) {
                size_t ad = ((size_t)b * C_ + oc + reg) * HW_ + p;
                out[ad] = a[reg] + br[reg] + x[ad];
            }
        }
    }
}

// ---------------------------------------------------------------------------
// Launch
// ---------------------------------------------------------------------------
extern "C" void kernel_launch(void* const* d_in, const int* in_sizes, int n_in,
                              void* d_out, int out_size, void* d_ws, size_t ws_size,
                              hipStream_t stream) {
    const float* x    = (const float*)d_in[0];
    const float* Wv   = (const float*)d_in[1];
    const float* bv   = (const float*)d_in[2];
    const float* Woff = (const float*)d_in[3];
    const float* boff = (const float*)d_in[4];
    const float* Wa   = (const float*)d_in[5];
    const float* ba   = (const float*)d_in[6];
    const float* Wo   = (const float*)d_in[7];
    const float* bo   = (const float*)d_in[8];
    float* out = (float*)d_out;
    char* base = (char*)d_ws;

    short* WcatBf = (short*)(base);               //   196608
    short* WoBf   = (short*)(base + 196608);      //   131072
    float* bcat   = (float*)(base + 327680);      //     1536 (+pad)
    short* xT     = (short*)(base + 329728);      // 26214400
    short* val    = (short*)(base + 26544128);    // 26214400
    float* meta   = (float*)(base + 52758528);    // 19660800
    short* wbuf   = (short*)(base + 72419328);    // 26214400

    prep_w<<<dim3(640), dim3(256), 0, stream>>>(Wv, bv, Woff, boff, Wa, ba, Wo,
                                                WcatBf, WoBf, bcat);
    transpose_x<<<dim3(100, 4, 8), dim3(256), 0, stream>>>(x, xT);
    gemm_proj_mfma<<<dim3(1200), dim3(256), 0, stream>>>(WcatBf, bcat, xT, val, meta);
    sample_kern<<<dim3(6400), dim3(256), 0, stream>>>(val, meta, wbuf);
    gemm_out_mfma<<<dim3(1600), dim3(256), 0, stream>>>(WoBf, bo, wbuf, x, out);
}

// Round 5
// 100.875 us; speedup vs baseline: 4.1543x; 1.0844x over previous
//
#include <hip/hip_runtime.h>
#include <cstddef>
#include <cstdint>

#define B_    8
#define C_    256
#define Himg  80
#define Wimg  80
#define HW_   6400
#define NH_   8
#define NP_   4
#define MPROJ 352

using bf16x8 = __attribute__((ext_vector_type(8))) short;
using f32x4  = __attribute__((ext_vector_type(4))) float;

__device__ __forceinline__ unsigned short f2bf(float f) {
    union { float f; uint32_t u; } v; v.f = f;
    uint32_t r = v.u + 0x7FFFu + ((v.u >> 16) & 1u);
    return (unsigned short)(r >> 16);
}
__device__ __forceinline__ float bf2f(unsigned short s) {
    union { uint32_t u; float f; } v; v.u = ((uint32_t)s) << 16;
    return v.f;
}

#define GLD16(gsrc, ldst) \
    __builtin_amdgcn_global_load_lds( \
        (const __attribute__((address_space(1))) unsigned int*)(gsrc), \
        (__attribute__((address_space(3))) unsigned int*)(ldst), 16, 0, 0)

// ---------------------------------------------------------------------------
// Kernel 0: fused weight-prep (blocks 0..639) + x transpose (blocks 640..3839).
// ---------------------------------------------------------------------------
__global__ __launch_bounds__(256) void prep_and_transpose(
        const float* __restrict__ Wv,  const float* __restrict__ bv,
        const float* __restrict__ Woff, const float* __restrict__ boff,
        const float* __restrict__ Wa,  const float* __restrict__ ba,
        const float* __restrict__ Wo,  const float* __restrict__ x,
        short* __restrict__ WcatBf, short* __restrict__ WoBf,
        float* __restrict__ bcat,   short* __restrict__ xT) {
    __shared__ float tile[64][68];
    const int bid = blockIdx.x;
    const int t = threadIdx.x;
    if (bid < 640) {
        int o = bid;
        if (o < 384) {
            const float* src = nullptr; float bias = 0.f;
            if (o < 256)      { src = Wv   + (size_t)o * 256;         bias = bv[o];         }
            else if (o < 320) { src = Woff + (size_t)(o - 256) * 256; bias = boff[o - 256]; }
            else if (o < 352) { src = Wa   + (size_t)(o - 320) * 256; bias = ba[o - 320];   }
            WcatBf[(size_t)o * 256 + t] = src ? (short)f2bf(src[t]) : (short)0;
            if (t == 0) bcat[o] = bias;
        } else {
            int oo = o - 384;
            WoBf[(size_t)oo * 256 + t] = (short)f2bf(Wo[(size_t)oo * 256 + t]);
        }
        return;
    }
    const int b2 = bid - 640;
    const int p0 = (b2 % 100) * 64;
    const int k0 = ((b2 / 100) & 3) * 64;
    const int b  = b2 / 400;
    const float* xb = x + ((size_t)b * C_ + k0) * HW_ + p0;
    #pragma unroll
    for (int r = 0; r < 4; ++r) {
        int kk = r * 16 + (t >> 4);
        int pp = (t & 15) * 4;
        float4 v = *(const float4*)(xb + (size_t)kk * HW_ + pp);
        *(float4*)&tile[kk][pp] = v;
    }
    __syncthreads();
    const int pp = t >> 2, kc = (t & 3) * 16;
    short tmp[16];
    #pragma unroll
    for (int i = 0; i < 16; ++i) tmp[i] = (short)f2bf(tile[kc + i][pp]);
    short* dst = xT + ((size_t)b * HW_ + p0 + pp) * 256 + k0 + kc;
    *(bf16x8*)dst       = *(bf16x8*)tmp;
    *(bf16x8*)(dst + 8) = *(bf16x8*)(tmp + 8);
}

// ---------------------------------------------------------------------------
// Kernel 1: projection GEMM, 128(o) x 128(p), BK=64, 2-phase pipelined.
// Epilogue: value channels -> head-major bf16 val[b][h][p][32];
//           offsets -> meta[0..63] pre-scaled by 39.5;
//           attn logits -> softmax'd in-register -> meta[64..95].
// ---------------------------------------------------------------------------
#define PSTAGE(buf, k0)                                                         \
    _Pragma("unroll")                                                           \
    for (int q = 0; q < 4; ++q) {                                               \
        int i = wid * 4 + q;                                                    \
        int row = i * 8 + (lane >> 3);                                          \
        int sc  = (lane & 7) ^ (row & 7);                                       \
        GLD16(Wb  + (size_t)(o0 + row) * 256 + (k0) + sc * 8,                   \
              &lA[(buf)][i * 512]);                                             \
        GLD16(xTb + (size_t)(p0 + row) * 256 + (k0) + sc * 8,                   \
              &lB[(buf)][i * 512]);                                             \
    }

#define PCOMPUTE(buf)                                                           \
    _Pragma("unroll")                                                           \
    for (int kk = 0; kk < 2; ++kk) {                                            \
        bf16x8 af[4], bfr[4];                                                   \
        _Pragma("unroll")                                                       \
        for (int m = 0; m < 4; ++m) {                                           \
            int row = wo0 + m * 16 + (lane & 15);                               \
            int cph = (kk * 4 + (lane >> 4)) ^ (row & 7);                       \
            af[m] = *(const bf16x8*)&lA[(buf)][row * 64 + cph * 8];             \
        }                                                                       \
        _Pragma("unroll")                                                       \
        for (int nn = 0; nn < 4; ++nn) {                                        \
            int row = wp0 + nn * 16 + (lane & 15);                              \
            int cph = (kk * 4 + (lane >> 4)) ^ (row & 7);                       \
            bfr[nn] = *(const bf16x8*)&lB[(buf)][row * 64 + cph * 8];           \
        }                                                                       \
        _Pragma("unroll")                                                       \
        for (int m = 0; m < 4; ++m)                                             \
            _Pragma("unroll")                                                   \
            for (int nn = 0; nn < 4; ++nn)                                      \
                acc[m][nn] = __builtin_amdgcn_mfma_f32_16x16x32_bf16(           \
                    af[m], bfr[nn], acc[m][nn], 0, 0, 0);                       \
    }

__global__ __launch_bounds__(256) void gemm_proj_mfma(
        const short* __restrict__ Wb, const float* __restrict__ bcat,
        const short* __restrict__ xT,
        short* __restrict__ val, float* __restrict__ meta) {
    __shared__ short lA[2][8192];
    __shared__ short lB[2][8192];
    const int n = blockIdx.x;
    const int w = (n & 7) * 150 + (n >> 3);
    const int b = w / 150;
    const int r150 = w % 150;
    const int o0 = (r150 / 50) * 128;
    const int p0 = (r150 % 50) * 128;
    const int t = threadIdx.x;
    const int wid = t >> 6, lane = t & 63;
    const int wo0 = (wid & 1) * 64, wp0 = (wid >> 1) * 64;
    const short* xTb = xT + (size_t)b * HW_ * 256;
    f32x4 acc[4][4] = {};

    PSTAGE(0, 0)
    __syncthreads();
    #pragma unroll
    for (int kt = 0; kt < 3; ++kt) {
        const int cur = kt & 1;
        PSTAGE(cur ^ 1, (kt + 1) * 64)
        PCOMPUTE(cur)
        __syncthreads();
    }
    PCOMPUTE(1)

    #pragma unroll
    for (int m = 0; m < 4; ++m) {
        int oc = o0 + wo0 + m * 16 + (lane >> 4) * 4;
        if (oc >= MPROJ) continue;
        float4 bias = *(const float4*)(bcat + oc);
        #pragma unroll
        for (int nn = 0; nn < 4; ++nn) {
            int p = p0 + wp0 + nn * 16 + (lane & 15);
            f32x4 a = acc[m][nn];
            float v0 = a[0] + bias.x, v1 = a[1] + bias.y;
            float v2 = a[2] + bias.z, v3 = a[3] + bias.w;
            if (oc < 256) {
                // head-major value store: val[b][h][p][32]
                int h = oc >> 5, c0 = oc & 31;
                ushort4 u;
                u.x = f2bf(v0); u.y = f2bf(v1); u.z = f2bf(v2); u.w = f2bf(v3);
                *(ushort4*)(val + (((size_t)(b * NH_ + h) * HW_) + p) * 32 + c0) = u;
            } else if (oc < 320) {
                // offsets, pre-scaled by 0.5*(dim-1) = 39.5
                float4 f;
                f.x = v0 * 39.5f; f.y = v1 * 39.5f;
                f.z = v2 * 39.5f; f.w = v3 * 39.5f;
                *(float4*)(meta + ((size_t)b * HW_ + p) * 96 + (oc - 256)) = f;
            } else {
                // attn logits -> softmax over the 4 points (one head per lane-quad)
                float mx = fmaxf(fmaxf(v0, v1), fmaxf(v2, v3));
                float e0 = __expf(v0 - mx), e1 = __expf(v1 - mx);
                float e2 = __expf(v2 - mx), e3 = __expf(v3 - mx);
                float inv = 1.f / (e0 + e1 + e2 + e3);
                float4 f;
                f.x = e0 * inv; f.y = e1 * inv; f.z = e2 * inv; f.w = e3 * inv;
                *(float4*)(meta + ((size_t)b * HW_ + p) * 96 + (oc - 256)) = f;
            }
        }
    }
}

// ---------------------------------------------------------------------------
// Kernel 2: bilinear sampling + point-weighted sum (softmax precomputed).
// Wave = 2 pixels; lane&31: h=(li>>2), j=li&3 -> channels j*8..j*8+7 (16B).
// val is head-major: corner chunk = 64B, x0/x1 corners contiguous (128B).
// ---------------------------------------------------------------------------
__global__ __launch_bounds__(256) void sample_kern(
        const short* __restrict__ val, const float* __restrict__ meta,
        short* __restrict__ wout) {
    const int t = threadIdx.x;
    const int wid = t >> 6, lane = t & 63;
    const int sub = lane >> 5, li = lane & 31;
    const int h = li >> 2, j = li & 3;
    const int orig = blockIdx.x;
    const int b = orig & 7;
    const int p = (orig >> 3) * 8 + wid * 2 + sub;
    const int yy = p / Wimg;
    const int xx = p - yy * Wimg;

    const float* mrow = meta + ((size_t)b * HW_ + p) * 96;
    float4 wv = *(const float4*)(mrow + 64 + h * 4);
    float wgt[4] = {wv.x, wv.y, wv.z, wv.w};

    float4 offA = *(const float4*)(mrow + h * 8);
    float4 offB = *(const float4*)(mrow + h * 8 + 4);
    float ox[4] = {offA.x, offA.z, offB.x, offB.z};
    float oy[4] = {offA.y, offA.w, offB.y, offB.w};

    const short* vb = val + ((size_t)(b * NH_ + h) * HW_) * 32 + j * 8;

    float acc[8] = {};
    #pragma unroll
    for (int pt = 0; pt < NP_; ++pt) {
        float ix = (float)xx + ox[pt];
        float iy = (float)yy + oy[pt];
        float x0f = floorf(ix), y0f = floorf(iy);
        int   x0  = (int)x0f,   y0  = (int)y0f;
        float wx1 = ix - x0f, wx0 = 1.f - wx1;
        float wy1 = iy - y0f, wy0 = 1.f - wy1;
        int x0c = min(max(x0, 0), Wimg - 1), x1c = min(max(x0 + 1, 0), Wimg - 1);
        int y0c = min(max(y0, 0), Himg - 1), y1c = min(max(y0 + 1, 0), Himg - 1);
        float vx0 = (x0 >= 0 && x0 <= Wimg - 1)         ? wx0 : 0.f;
        float vx1 = (x0 + 1 >= 0 && x0 + 1 <= Wimg - 1) ? wx1 : 0.f;
        float vy0 = (y0 >= 0 && y0 <= Himg - 1)         ? wy0 : 0.f;
        float vy1 = (y0 + 1 >= 0 && y0 + 1 <= Himg - 1) ? wy1 : 0.f;
        bf16x8 u00 = *(const bf16x8*)(vb + (size_t)(y0c * Wimg + x0c) * 32);
        bf16x8 u01 = *(const bf16x8*)(vb + (size_t)(y0c * Wimg + x1c) * 32);
        bf16x8 u10 = *(const bf16x8*)(vb + (size_t)(y1c * Wimg + x0c) * 32);
        bf16x8 u11 = *(const bf16x8*)(vb + (size_t)(y1c * Wimg + x1c) * 32);
        float w00 = vy0 * vx0 * wgt[pt], w01 = vy0 * vx1 * wgt[pt];
        float w10 = vy1 * vx0 * wgt[pt], w11 = vy1 * vx1 * wgt[pt];
        #pragma unroll
        for (int c = 0; c < 8; ++c) {
            acc[c] += w00 * bf2f((unsigned short)u00[c])
                    + w01 * bf2f((unsigned short)u01[c])
                    + w10 * bf2f((unsigned short)u10[c])
                    + w11 * bf2f((unsigned short)u11[c]);
        }
    }
    short tmp[8];
    #pragma unroll
    for (int c = 0; c < 8; ++c) tmp[c] = (short)f2bf(acc[c]);
    *(bf16x8*)(wout + ((size_t)b * HW_ + p) * 256 + h * 32 + j * 8) = *(bf16x8*)tmp;
}

// ---------------------------------------------------------------------------
// Kernel 3: output GEMM + bias + residual, 64(o) x 128(p), BK=64, 2-phase.
// ---------------------------------------------------------------------------
#define OSTAGE(buf, k0)                                                         \
    _Pragma("unroll")                                                           \
    for (int q = 0; q < 2; ++q) {                                               \
        int i = wid * 2 + q;                                                    \
        int row = i * 8 + (lane >> 3);                                          \
        int sc  = (lane & 7) ^ (row & 7);                                       \
        GLD16(Wb + (size_t)(o0 + row) * 256 + (k0) + sc * 8,                    \
              &lA[(buf)][i * 512]);                                             \
    }                                                                           \
    _Pragma("unroll")                                                           \
    for (int q = 0; q < 4; ++q) {                                               \
        int i = wid * 4 + q;                                                    \
        int row = i * 8 + (lane >> 3);                                          \
        int sc  = (lane & 7) ^ (row & 7);                                       \
        GLD16(wgtb + (size_t)(p0 + row) * 256 + (k0) + sc * 8,                  \
              &lB[(buf)][i * 512]);                                             \
    }

#define OCOMPUTE(buf)                                                           \
    _Pragma("unroll")                                                           \
    for (int kk = 0; kk < 2; ++kk) {                                            \
        bf16x8 af[4], bfr[2];                                                   \
        _Pragma("unroll")                                                       \
        for (int m = 0; m < 4; ++m) {                                           \
            int row = m * 16 + (lane & 15);                                     \
            int cph = (kk * 4 + (lane >> 4)) ^ (row & 7);                       \
            af[m] = *(const bf16x8*)&lA[(buf)][row * 64 + cph * 8];             \
        }                                                                       \
        _Pragma("unroll")                                                       \
        for (int nn = 0; nn < 2; ++nn) {                                        \
            int row = wid * 32 + nn * 16 + (lane & 15);                         \
            int cph = (kk * 4 + (lane >> 4)) ^ (row & 7);                       \
            bfr[nn] = *(const bf16x8*)&lB[(buf)][row * 64 + cph * 8];           \
        }                                                                       \
        _Pragma("unroll")                                                       \
        for (int m = 0; m < 4; ++m)                                             \
            _Pragma("unroll")                                                   \
            for (int nn = 0; nn < 2; ++nn)                                      \
                acc[m][nn] = __builtin_amdgcn_mfma_f32_16x16x32_bf16(           \
                    af[m], bfr[nn], acc[m][nn], 0, 0, 0);                       \
    }

__global__ __launch_bounds__(256) void gemm_out_mfma(
        const short* __restrict__ Wb, const float* __restrict__ bo,
        const short* __restrict__ wgt, const float* __restrict__ x,
        float* __restrict__ out) {
    __shared__ short lA[2][4096];
    __shared__ short lB[2][8192];
    const int n = blockIdx.x;               // 0..1599
    const int w = (n & 7) * 200 + (n >> 3);
    const int b = w / 200;
    const int r200 = w % 200;
    const int o0 = (r200 / 50) * 64;
    const int p0 = (r200 % 50) * 128;
    const int t = threadIdx.x;
    const int wid = t >> 6, lane = t & 63;
    const short* wgtb = wgt + (size_t)b * HW_ * 256;
    f32x4 acc[4][2] = {};

    OSTAGE(0, 0)
    __syncthreads();
    #pragma unroll
    for (int kt = 0; kt < 3; ++kt) {
        const int cur = kt & 1;
        OSTAGE(cur ^ 1, (kt + 1) * 64)
        OCOMPUTE(cur)
        __syncthreads();
    }
    OCOMPUTE(1)

    #pragma unroll
    for (int m = 0; m < 4; ++m) {
        int oc = o0 + m * 16 + (lane >> 4) * 4;
        float4 bias = *(const float4*)(bo + oc);
        float br[4] = {bias.x, bias.y, bias.z, bias.w};
        #pragma unroll
        for (int nn = 0; nn < 2; ++nn) {
            int p = p0 + wid * 32 + nn * 16 + (lane & 15);
            f32x4 a = acc[m][nn];
            #pragma unroll
            for (int reg = 0; reg < 4; ++reg) {
                size_t ad = ((size_t)b * C_ + oc + reg) * HW_ + p;
                out[ad] = a[reg] + br[reg] + x[ad];
            }
        }
    }
}

// ---------------------------------------------------------------------------
// Launch
// ---------------------------------------------------------------------------
extern "C" void kernel_launch(void* const* d_in, const int* in_sizes, int n_in,
                              void* d_out, int out_size, void* d_ws, size_t ws_size,
                              hipStream_t stream) {
    const float* x    = (const float*)d_in[0];
    const float* Wv   = (const float*)d_in[1];
    const float* bv   = (const float*)d_in[2];
    const float* Woff = (const float*)d_in[3];
    const float* boff = (const float*)d_in[4];
    const float* Wa   = (const float*)d_in[5];
    const float* ba   = (const float*)d_in[6];
    const float* Wo   = (const float*)d_in[7];
    const float* bo   = (const float*)d_in[8];
    float* out = (float*)d_out;
    char* base = (char*)d_ws;

    short* WcatBf = (short*)(base);               //   196608
    short* WoBf   = (short*)(base + 196608);      //   131072
    float* bcat   = (float*)(base + 327680);      //     1536 (+pad)
    short* xT     = (short*)(base + 329728);      // 26214400
    short* val    = (short*)(base + 26544128);    // 26214400
    float* meta   = (float*)(base + 52758528);    // 19660800
    short* wbuf   = (short*)(base + 72419328);    // 26214400

    prep_and_transpose<<<dim3(3840), dim3(256), 0, stream>>>(
        Wv, bv, Woff, boff, Wa, ba, Wo, x, WcatBf, WoBf, bcat, xT);
    gemm_proj_mfma<<<dim3(1200), dim3(256), 0, stream>>>(WcatBf, bcat, xT, val, meta);
    sample_kern<<<dim3(6400), dim3(256), 0, stream>>>(val, meta, wbuf);
    gemm_out_mfma<<<dim3(1600), dim3(256), 0, stream>>>(WoBf, bo, wbuf, x, out);
}